// Round 2
// baseline (273.484 us; speedup 1.0000x reference)
//
#include <hip/hip_runtime.h>

// PCEN: out = (x/(FLOOR+m)^alpha + delta)^(1/root) - delta^(1/root)
// m = EMA over T with s=0.025, m_0 = x_0.
// Shapes: x [B=64, T=4096, C=128] f32, alpha/delta/root [C] f32.

constexpr int Bn = 64, Tn = 4096, Cn = 128;
constexpr int NC = 64;            // chunks along T
constexpr int Lc = Tn / NC;       // 64 timesteps per chunk
constexpr float SC  = 0.025f;
constexpr float OMS = 1.0f - SC;  // 0.975
constexpr float FLOORV = 1e-6f;

// (1-s)^Lc, compile-time
__host__ __device__ constexpr float chunk_decay() {
    float a = 1.0f;
    for (int i = 0; i < Lc; ++i) a *= OMS;
    return a;
}
constexpr float ACH = chunk_decay();

// Thread mapping for k_partial / k_final:
//   gid = b*(NC*32) + chunk*32 + cg   (cg indexes a float4 group of channels)
// Consecutive lanes -> consecutive channels -> coalesced float4 accesses.

__global__ __launch_bounds__(256) void k_partial(const float* __restrict__ x,
                                                 float* __restrict__ endv) {
    int gid   = blockIdx.x * 256 + threadIdx.x;
    int cg    = gid & 31;
    int chunk = (gid >> 5) & (NC - 1);
    int b     = gid >> 11;

    const float4* xp = (const float4*)x + (size_t)(b * Tn + chunk * Lc) * (Cn / 4) + cg;

    // t = 0 peeled: chunk 0 starts with m = x_0 (a_0 = 0); others zero-init local scan.
    float4 v = xp[0];
    float4 m;
    if (chunk == 0) {
        m = v;
    } else {
        m.x = SC * v.x; m.y = SC * v.y; m.z = SC * v.z; m.w = SC * v.w;
    }
#pragma unroll 8
    for (int t = 1; t < Lc; ++t) {
        v = xp[(size_t)t * (Cn / 4)];
        m.x = fmaf(OMS, m.x, SC * v.x);
        m.y = fmaf(OMS, m.y, SC * v.y);
        m.z = fmaf(OMS, m.z, SC * v.z);
        m.w = fmaf(OMS, m.w, SC * v.w);
    }
    float4* ep = (float4*)endv + (size_t)(b * NC + chunk) * (Cn / 4) + cg;
    *ep = m;
}

// In-place: endv[b,j,c] (chunk-local end values) -> incoming prefix m_end[j-1].
// m_end_j = B_j + ACH * m_end_{j-1}; incoming for chunk j is m_end_{j-1} (0 for j=0).
__global__ __launch_bounds__(256) void k_scan(float* __restrict__ endv) {
    int gid = blockIdx.x * 256 + threadIdx.x;   // 2048 threads total
    int cg  = gid & 31;
    int b   = gid >> 5;
    float4* p = (float4*)endv + (size_t)b * NC * (Cn / 4) + cg;
    float4 acc = {0.f, 0.f, 0.f, 0.f};
    for (int j = 0; j < NC; ++j) {
        float4 e = p[(size_t)j * (Cn / 4)];
        p[(size_t)j * (Cn / 4)] = acc;          // incoming prefix for chunk j
        acc.x = fmaf(ACH, acc.x, e.x);
        acc.y = fmaf(ACH, acc.y, e.y);
        acc.z = fmaf(ACH, acc.z, e.z);
        acc.w = fmaf(ACH, acc.w, e.w);
    }
}

__device__ __forceinline__ float pcen_elem(float x, float m, float al, float dl,
                                           float oor, float t3) {
    float lg   = log2f(FLOORV + m);
    float inv1 = exp2f(-al * lg);               // 1 / (FLOOR+m)^alpha
    float base = fmaf(x, inv1, dl);             // x/term1 + delta  (>0)
    return exp2f(oor * log2f(base)) - t3;
}

__global__ __launch_bounds__(256) void k_final(const float* __restrict__ x,
                                               const float* __restrict__ alpha,
                                               const float* __restrict__ delta,
                                               const float* __restrict__ root,
                                               const float* __restrict__ inc,
                                               float* __restrict__ out) {
    int gid   = blockIdx.x * 256 + threadIdx.x;
    int cg    = gid & 31;
    int chunk = (gid >> 5) & (NC - 1);
    int b     = gid >> 11;
    int c0    = cg * 4;

    float4 al = *(const float4*)(alpha + c0);
    float4 dl = *(const float4*)(delta + c0);
    float4 rt = *(const float4*)(root + c0);
    al.x = fminf(al.x, 1.f); al.y = fminf(al.y, 1.f); al.z = fminf(al.z, 1.f); al.w = fminf(al.w, 1.f);
    rt.x = fmaxf(rt.x, 1.f); rt.y = fmaxf(rt.y, 1.f); rt.z = fmaxf(rt.z, 1.f); rt.w = fmaxf(rt.w, 1.f);
    float4 oor = {1.f / rt.x, 1.f / rt.y, 1.f / rt.z, 1.f / rt.w};
    float4 t3  = {exp2f(oor.x * log2f(dl.x)), exp2f(oor.y * log2f(dl.y)),
                  exp2f(oor.z * log2f(dl.z)), exp2f(oor.w * log2f(dl.w))};

    size_t xoff = (size_t)(b * Tn + chunk * Lc) * (Cn / 4) + cg;
    const float4* xp = (const float4*)x + xoff;
    float4*       op = (float4*)out + xoff;

    float4 m = *((const float4*)inc + (size_t)(b * NC + chunk) * (Cn / 4) + cg);

    // t = 0 peeled (chunk 0: m = x_0)
    float4 v = xp[0];
    if (chunk == 0) {
        m = v;
    } else {
        m.x = fmaf(OMS, m.x, SC * v.x);
        m.y = fmaf(OMS, m.y, SC * v.y);
        m.z = fmaf(OMS, m.z, SC * v.z);
        m.w = fmaf(OMS, m.w, SC * v.w);
    }
    float4 o;
    o.x = pcen_elem(v.x, m.x, al.x, dl.x, oor.x, t3.x);
    o.y = pcen_elem(v.y, m.y, al.y, dl.y, oor.y, t3.y);
    o.z = pcen_elem(v.z, m.z, al.z, dl.z, oor.z, t3.z);
    o.w = pcen_elem(v.w, m.w, al.w, dl.w, oor.w, t3.w);
    op[0] = o;

#pragma unroll 4
    for (int t = 1; t < Lc; ++t) {
        v = xp[(size_t)t * (Cn / 4)];
        m.x = fmaf(OMS, m.x, SC * v.x);
        m.y = fmaf(OMS, m.y, SC * v.y);
        m.z = fmaf(OMS, m.z, SC * v.z);
        m.w = fmaf(OMS, m.w, SC * v.w);
        o.x = pcen_elem(v.x, m.x, al.x, dl.x, oor.x, t3.x);
        o.y = pcen_elem(v.y, m.y, al.y, dl.y, oor.y, t3.y);
        o.z = pcen_elem(v.z, m.z, al.z, dl.z, oor.z, t3.z);
        o.w = pcen_elem(v.w, m.w, al.w, dl.w, oor.w, t3.w);
        op[(size_t)t * (Cn / 4)] = o;
    }
}

extern "C" void kernel_launch(void* const* d_in, const int* in_sizes, int n_in,
                              void* d_out, int out_size, void* d_ws, size_t ws_size,
                              hipStream_t stream) {
    const float* x     = (const float*)d_in[0];
    const float* alpha = (const float*)d_in[1];
    const float* delta = (const float*)d_in[2];
    const float* root  = (const float*)d_in[3];
    float* out = (float*)d_out;
    float* ws  = (float*)d_ws;   // needs B*NC*C*4 = 2 MiB

    const int total = Bn * NC * (Cn / 4);        // 131072 threads
    k_partial<<<total / 256, 256, 0, stream>>>(x, ws);
    k_scan<<<(Bn * (Cn / 4)) / 256, 256, 0, stream>>>(ws);
    k_final<<<total / 256, 256, 0, stream>>>(x, alpha, delta, root, ws, out);
}